// Round 3
// baseline (85.097 us; speedup 1.0000x reference)
//
#include <hip/hip_runtime.h>
#include <math.h>

// Output layout: [N][X=32][Y=32][Z=32][3] float32, N=1024.
// val[n,x,y,z,d] = -0.5*t^2 - 0.5*log(2*pi),
//   t = idx_d*s - b_d,  s = pitch*inv,  b_d = (15.5*pitch + p[n,d])*inv,
//   inv = 1/(conf[n]*pitch)   (ALPHA = 1)
//
// Key structure: for fixed n, the value only depends on (axis d, index along
// that axis). Per thread, the (y,z,d) sub-pattern of its 12 output slots is
// invariant across x — precompute it once, then each x-slab is 12 FMAs + 3
// non-temporal 16B stores.

#define HALF_LOG_2PI 0.91893853320467274178f

typedef float f32x4 __attribute__((ext_vector_type(4)));

__global__ __launch_bounds__(256) void pbt_kernel(
    const float* __restrict__ points,
    const float* __restrict__ confs,
    const float* __restrict__ pitch_p,
    float* __restrict__ out)
{
    const unsigned n = blockIdx.x;          // one block per point n
    const unsigned t = threadIdx.x;

    const float pitch = pitch_p[0];
    const float conf  = confs[n];
    const float inv   = 1.0f / (conf * pitch);
    const float s     = pitch * inv;
    const float off   = 15.5f * pitch;
    const float bx = (off + points[n * 3 + 0]) * inv;
    const float by = (off + points[n * 3 + 1]) * inv;
    const float bz = (off + points[n * 3 + 2]) * inv;

    // This thread owns float4 slots f4 = t + k*256 (k=0..2) within each
    // 3072-float x-slab. Element e = f4*4 + j; d = e%3; zi = e/3;
    // y = zi>>5; z = zi&31. Precompute the x-invariant part.
    float vbase[3][4];  // (d==0) ? 0.0 : logprob of the y/z coordinate
    float isx[3][4];    // 1.0 where d==0, else 0.0
    #pragma unroll
    for (int k = 0; k < 3; ++k) {
        const unsigned e0 = (t + (unsigned)k * 256u) * 4u;
        #pragma unroll
        for (int j = 0; j < 4; ++j) {
            const unsigned e  = e0 + (unsigned)j;
            const unsigned d  = e % 3u;
            const unsigned zi = e / 3u;
            const unsigned y  = zi >> 5;
            const unsigned zz = zi & 31u;
            const float c  = (d == 2u) ? (float)zz : (float)y;
            const float b  = (d == 2u) ? bz : by;
            const float tc = c * s - b;
            const float v  = fmaf(-0.5f * tc, tc, -HALF_LOG_2PI);
            isx[k][j]   = (d == 0u) ? 1.0f : 0.0f;
            vbase[k][j] = (d == 0u) ? 0.0f : v;
        }
    }

    // Stream 32 x-slabs: 98304 floats = 24576 float4s per n.
    f32x4* o = (f32x4*)(out + (size_t)n * 98304u) + t;
    #pragma unroll 2
    for (unsigned x = 0; x < 32u; ++x) {
        const float tx = (float)x * s - bx;
        const float vx = fmaf(-0.5f * tx, tx, -HALF_LOG_2PI);
        f32x4* ox = o + (size_t)x * 768u;
        #pragma unroll
        for (int k = 0; k < 3; ++k) {
            f32x4 v;
            v.x = fmaf(isx[k][0], vx, vbase[k][0]);
            v.y = fmaf(isx[k][1], vx, vbase[k][1]);
            v.z = fmaf(isx[k][2], vx, vbase[k][2]);
            v.w = fmaf(isx[k][3], vx, vbase[k][3]);
            __builtin_nontemporal_store(v, ox + k * 256);
        }
    }
}

extern "C" void kernel_launch(void* const* d_in, const int* in_sizes, int n_in,
                              void* d_out, int out_size, void* d_ws, size_t ws_size,
                              hipStream_t stream) {
    const float* points = (const float*)d_in[0];  // [N,3]
    const float* confs  = (const float*)d_in[1];  // [N]
    // d_in[2] = coordinates [32,32,32,3] — recomputed from pitch on device
    const float* pitch  = (const float*)d_in[3];  // [1]
    float* out = (float*)d_out;

    const int N = in_sizes[0] / 3;        // 1024
    pbt_kernel<<<dim3(N), dim3(256), 0, stream>>>(points, confs, pitch, out);
}

// Round 4
// 80.549 us; speedup vs baseline: 1.0565x; 1.0565x over previous
//
#include <hip/hip_runtime.h>
#include <math.h>

// Output layout: [N][X=32][Y=32][Z=32][3] float32, N=1024.
// val[n,x,y,z,d] = -0.5*t^2 - 0.5*log(2*pi),
//   t = idx_d*s - b_d,  s = pitch*inv,  b_d = (15.5*pitch + p[n,d])*inv,
//   inv = 1/(conf[n]*pitch)   (ALPHA = 1)
//
// R3 experiment: identical to R2 except PLAIN stores (no nontemporal flag) —
// single-variable test of whether the 'nt' bit caused the R0->R2 regression.

#define HALF_LOG_2PI 0.91893853320467274178f

typedef float f32x4 __attribute__((ext_vector_type(4)));

__global__ __launch_bounds__(256) void pbt_kernel(
    const float* __restrict__ points,
    const float* __restrict__ confs,
    const float* __restrict__ pitch_p,
    float* __restrict__ out)
{
    const unsigned n = blockIdx.x;          // one block per point n
    const unsigned t = threadIdx.x;

    const float pitch = pitch_p[0];
    const float conf  = confs[n];
    const float inv   = 1.0f / (conf * pitch);
    const float s     = pitch * inv;
    const float off   = 15.5f * pitch;
    const float bx = (off + points[n * 3 + 0]) * inv;
    const float by = (off + points[n * 3 + 1]) * inv;
    const float bz = (off + points[n * 3 + 2]) * inv;

    // This thread owns float4 slots f4 = t + k*256 (k=0..2) within each
    // 3072-float x-slab. Element e = f4*4 + j; d = e%3; zi = e/3;
    // y = zi>>5; z = zi&31. Precompute the x-invariant part.
    float vbase[3][4];  // (d==0) ? 0.0 : logprob of the y/z coordinate
    float isx[3][4];    // 1.0 where d==0, else 0.0
    #pragma unroll
    for (int k = 0; k < 3; ++k) {
        const unsigned e0 = (t + (unsigned)k * 256u) * 4u;
        #pragma unroll
        for (int j = 0; j < 4; ++j) {
            const unsigned e  = e0 + (unsigned)j;
            const unsigned d  = e % 3u;
            const unsigned zi = e / 3u;
            const unsigned y  = zi >> 5;
            const unsigned zz = zi & 31u;
            const float c  = (d == 2u) ? (float)zz : (float)y;
            const float b  = (d == 2u) ? bz : by;
            const float tc = c * s - b;
            const float v  = fmaf(-0.5f * tc, tc, -HALF_LOG_2PI);
            isx[k][j]   = (d == 0u) ? 1.0f : 0.0f;
            vbase[k][j] = (d == 0u) ? 0.0f : v;
        }
    }

    // Stream 32 x-slabs: 98304 floats = 24576 float4s per n.
    f32x4* o = (f32x4*)(out + (size_t)n * 98304u) + t;
    #pragma unroll 2
    for (unsigned x = 0; x < 32u; ++x) {
        const float tx = (float)x * s - bx;
        const float vx = fmaf(-0.5f * tx, tx, -HALF_LOG_2PI);
        f32x4* ox = o + (size_t)x * 768u;
        #pragma unroll
        for (int k = 0; k < 3; ++k) {
            f32x4 v;
            v.x = fmaf(isx[k][0], vx, vbase[k][0]);
            v.y = fmaf(isx[k][1], vx, vbase[k][1]);
            v.z = fmaf(isx[k][2], vx, vbase[k][2]);
            v.w = fmaf(isx[k][3], vx, vbase[k][3]);
            ox[k * 256] = v;   // plain store (global_store_dwordx4, no nt)
        }
    }
}

extern "C" void kernel_launch(void* const* d_in, const int* in_sizes, int n_in,
                              void* d_out, int out_size, void* d_ws, size_t ws_size,
                              hipStream_t stream) {
    const float* points = (const float*)d_in[0];  // [N,3]
    const float* confs  = (const float*)d_in[1];  // [N]
    // d_in[2] = coordinates [32,32,32,3] — recomputed from pitch on device
    const float* pitch  = (const float*)d_in[3];  // [1]
    float* out = (float*)d_out;

    const int N = in_sizes[0] / 3;        // 1024
    pbt_kernel<<<dim3(N), dim3(256), 0, stream>>>(points, confs, pitch, out);
}